// Round 5
// baseline (12421.432 us; speedup 1.0000x reference)
//
#include <hip/hip_runtime.h>
#include <hip/hip_bf16.h>

// GraphBertEncoder: T=32768 tokens, S=6, D=256, H=8 (hd=32), L=4.
// Round 5: 3 blocks/CU (LDS 52KB, VGPR cap 170), warp-local attention (no
// attw LDS, no intra-attention barriers), cross-phase weight prefetch,
// s_setprio around MFMA clusters. Weights pre-packed bf16 fragment-linear.

#define TB 4
#define NROW 24

typedef float f32x4 __attribute__((ext_vector_type(4)));
typedef short bfv8  __attribute__((ext_vector_type(8)));   // 8 bf16 = 4 VGPR

__device__ __forceinline__ float bf2f(__hip_bfloat16 v) { return __bfloat162float(v); }
__device__ __forceinline__ __hip_bfloat16 f2bf(float v) { return __float2bfloat16(v); }
__device__ __forceinline__ float bfs2f(short s) { return __uint_as_float(((unsigned)(unsigned short)s) << 16); }
// swizzled byte offset into a [rows][512B] bf16 tile
__device__ __forceinline__ int swz(int row, int cb) { return row*512 + (cb ^ ((row & 7) << 4)); }
__device__ __forceinline__ float gelu_f(float v) { return 0.5f*v*(1.f + erff(v*0.70710678118654752f)); }
__device__ __forceinline__ float unpk(unsigned p, int hi) {
  return __uint_as_float(hi ? (p & 0xffff0000u) : (p << 16));
}

// ws fragment-layout offsets (bf16 elements)
#define OWQ 0u
#define OWO 786432u
#define OW1 1048576u
#define OW2 2097152u
#define WS_ELEMS 3145728u   // *2B = 6291456 bytes

// LDS layout (bytes)
#define O_HSB 0
#define O_R1  12288   // q | o | gelu-buf0 | xbuf(embed)
#define O_R2  24576   // k | fbuf(fp32, spans R2+R3) | gelu-buf1
#define O_R3  36864   // v
#define O_RED 49152   // 192 floats
#define SMEM_SZ 53248 // slack so row-24..31 overreads stay in-bounds

// ---------------------------------------------------------------------------
// prep: fp32 weights -> bf16 B-fragment-linear in ws.
// fragment f of a KxN weight: lane l, j holds W[ks*32+(l>>4)*8+j][nt*16+(l&15)]
// stored at base + f*512 + l*8 + j, f = nt*(K/32) + ks.
__global__ __launch_bounds__(256) void gb_prep_kernel(
    const float* __restrict__ Wqkv, const float* __restrict__ Wo,
    const float* __restrict__ W1,   const float* __restrict__ W2,
    __hip_bfloat16* __restrict__ ws)
{
  int fg   = blockIdx.x * 4 + (threadIdx.x >> 6);   // 0..6143
  int lane = threadIdx.x & 63;
  int layer = fg / 1536, r = fg % 1536;
  const float* src; int K, N, fl; unsigned dstbase;
  if (r < 384)       { src = Wqkv + layer*196608; K = 256;  N = 768;  fl = r;       dstbase = OWQ + layer*196608u; }
  else if (r < 512)  { src = Wo   + layer*65536;  K = 256;  N = 256;  fl = r - 384; dstbase = OWO + layer*65536u;  }
  else if (r < 1024) { src = W1   + layer*262144; K = 256;  N = 1024; fl = r - 512; dstbase = OW1 + layer*262144u; }
  else               { src = W2   + layer*262144; K = 1024; N = 256;  fl = r - 1024;dstbase = OW2 + layer*262144u; }
  int nk = K >> 5;
  int nt = fl / nk, ks = fl % nk;
  int n  = nt*16 + (lane & 15);
  int k0 = ks*32 + (lane >> 4)*8;
  __align__(16) __hip_bfloat16 tmp[8];
  #pragma unroll
  for (int j = 0; j < 8; ++j) tmp[j] = f2bf(src[(size_t)(k0 + j)*N + n]);
  *(uint4*)(ws + dstbase + (unsigned)fl*512u + lane*8) = *(const uint4*)tmp;
}

// ---------------------------------------------------------------------------
__device__ __forceinline__ void preload8(const __hip_bfloat16* __restrict__ p, bfv8 (&b)[8]) {
  #pragma unroll
  for (int k = 0; k < 8; ++k) b[k] = *(const bfv8*)(p + k*512);
}

// one-pass LayerNorm over 256 columns for 24 rows (thread owns column tid).
__device__ __forceinline__ void ln24_norm(float* z, float* redbuf, float g, float b, int tid) {
  const int lane = tid & 63, wid = tid >> 6;
  float s1[NROW], s2[NROW];
  #pragma unroll
  for (int r = 0; r < NROW; ++r) { float v = z[r]; s1[r] = v; s2[r] = v*v; }
  #pragma unroll
  for (int off = 32; off; off >>= 1) {
    #pragma unroll
    for (int r = 0; r < NROW; ++r) {
      s1[r] += __shfl_down(s1[r], off, 64);
      s2[r] += __shfl_down(s2[r], off, 64);
    }
  }
  if (lane == 0) {
    #pragma unroll
    for (int r = 0; r < NROW; ++r) { redbuf[wid*48 + r] = s1[r]; redbuf[wid*48 + 24 + r] = s2[r]; }
  }
  __syncthreads();
  #pragma unroll
  for (int r = 0; r < NROW; ++r) {
    float S1 = redbuf[r] + redbuf[48+r] + redbuf[96+r] + redbuf[144+r];
    float S2 = redbuf[24+r] + redbuf[72+r] + redbuf[120+r] + redbuf[168+r];
    float m  = S1 * (1.0f/256.0f);
    float var = S2 * (1.0f/256.0f) - m*m;
    float iv = rsqrtf(var + 1e-5f);
    z[r] = (z[r] - m) * iv * g + b;
  }
  __syncthreads();
}

// ---------------------------------------------------------------------------
// GEMM section: per wave, NTI n-tiles (nt = wid + 4*i), K=256 (8 fragments).
// bA arrives preloaded (possibly issued phases earlier); double-buffered
// prefetch; 4 independent MFMA chains; s_setprio(1) around clusters.
template<int NTI, int NKTOT, class Epi>
__device__ __forceinline__ void gemm_sec(const __hip_bfloat16* __restrict__ p,
                                         bfv8 (&bA)[8],
                                         const bfv8 (&a0)[8], const bfv8 (&a1)[8],
                                         Epi epi)
{
  bfv8 bB[8];
  #pragma unroll
  for (int i = 0; i < NTI; i += 2) {
    preload8(p + (unsigned)(i+1)*4u*(unsigned)NKTOT*512u, bB);
    {
      __builtin_amdgcn_s_setprio(1);
      f32x4 c0a = {0,0,0,0}, c0b = {0,0,0,0}, c1a = {0,0,0,0}, c1b = {0,0,0,0};
      #pragma unroll
      for (int k = 0; k < 8; k += 2) {
        c0a = __builtin_amdgcn_mfma_f32_16x16x32_bf16(a0[k],   bA[k],   c0a, 0,0,0);
        c1a = __builtin_amdgcn_mfma_f32_16x16x32_bf16(a1[k],   bA[k],   c1a, 0,0,0);
        c0b = __builtin_amdgcn_mfma_f32_16x16x32_bf16(a0[k+1], bA[k+1], c0b, 0,0,0);
        c1b = __builtin_amdgcn_mfma_f32_16x16x32_bf16(a1[k+1], bA[k+1], c1b, 0,0,0);
      }
      __builtin_amdgcn_s_setprio(0);
      epi(i, c0a + c0b, c1a + c1b);
    }
    if (i + 2 < NTI) preload8(p + (unsigned)(i+2)*4u*(unsigned)NKTOT*512u, bA);
    {
      __builtin_amdgcn_s_setprio(1);
      f32x4 c0a = {0,0,0,0}, c0b = {0,0,0,0}, c1a = {0,0,0,0}, c1b = {0,0,0,0};
      #pragma unroll
      for (int k = 0; k < 8; k += 2) {
        c0a = __builtin_amdgcn_mfma_f32_16x16x32_bf16(a0[k],   bB[k],   c0a, 0,0,0);
        c1a = __builtin_amdgcn_mfma_f32_16x16x32_bf16(a1[k],   bB[k],   c1a, 0,0,0);
        c0b = __builtin_amdgcn_mfma_f32_16x16x32_bf16(a0[k+1], bB[k+1], c0b, 0,0,0);
        c1b = __builtin_amdgcn_mfma_f32_16x16x32_bf16(a1[k+1], bB[k+1], c1b, 0,0,0);
      }
      __builtin_amdgcn_s_setprio(0);
      epi(i+1, c0a + c0b, c1a + c1b);
    }
  }
}

// ---------------------------------------------------------------------------
__global__ __launch_bounds__(256, 3) void gb_mfma_kernel(
    const float* __restrict__ x,
    const float* __restrict__ W_raw, const float* __restrict__ b_raw,
    const float* __restrict__ wl_emb, const float* __restrict__ pos_emb,
    const float* __restrict__ hop_emb,
    const float* __restrict__ ln_g, const float* __restrict__ ln_b,
    const float* __restrict__ bqkv, const float* __restrict__ bo,
    const float* __restrict__ n1g,  const float* __restrict__ n1b,
    const float* __restrict__ b1,   const float* __restrict__ b2,
    const float* __restrict__ n2g,  const float* __restrict__ n2b,
    const float* __restrict__ W_res, const float* __restrict__ b_res,
    const __hip_bfloat16* __restrict__ wf,
    float* __restrict__ out)
{
  __shared__ __align__(16) char smem[SMEM_SZ];
  char* hsb = smem + O_HSB;                       // [24][512B] swz bf16 (h)
  char* uQ  = smem + O_R1;                        // q, later o / gelu0
  char* uK  = smem + O_R2;                        // k, later fbuf / gelu1
  char* uV  = smem + O_R3;                        // v
  float* redbuf = (float*)(smem + O_RED);
  float (*fbuf)[256] = (float (*)[256])(smem + O_R2);
  float (*xbuf)[128] = (float (*)[128])(smem + O_R1);

  const int tid  = threadIdx.x;
  const int bt   = blockIdx.x;
  const int lane = tid & 63, wid = tid >> 6;
  const int l15  = lane & 15, l4 = lane >> 4;

  // ---------------- Embedding: stage sub_x rows (fp32, idx mapping) --------
  for (int idx = tid; idx < TB*6*128; idx += 256) {
    int tt = idx / 768, rem = idx % 768;
    int s = rem >> 7, f = rem & 127;
    int t = bt*TB + tt, g = t >> 7, i = t & 127;
    int node;
    if (s < 2) node = i;
    else { int j = s - 2; node = (j < i) ? j : (j + 1); }
    xbuf[tt*6+s][f] = x[(g*128 + node)*128 + f];
  }
  __syncthreads();

  float z[NROW];
  {
    #pragma unroll
    for (int r = 0; r < NROW; ++r) z[r] = 0.f;
    #pragma unroll 2
    for (int f4 = 0; f4 < 32; ++f4) {
      float w0 = W_raw[(f4*4+0)*256 + tid];
      float w1 = W_raw[(f4*4+1)*256 + tid];
      float w2 = W_raw[(f4*4+2)*256 + tid];
      float w3 = W_raw[(f4*4+3)*256 + tid];
      #pragma unroll
      for (int r = 0; r < NROW; ++r) {
        float4 xv = *(const float4*)(&xbuf[r][f4*4]);
        z[r] += xv.x*w0 + xv.y*w1 + xv.z*w2 + xv.w*w3;
      }
    }
    float br  = b_raw[tid];
    float wl  = wl_emb[tid];
    float hp0 = hop_emb[5*256 + tid];
    float hp1 = hop_emb[511*256 + tid];
    float p[6];
    #pragma unroll
    for (int s = 0; s < 6; ++s) p[s] = pos_emb[s*256 + tid];
    #pragma unroll
    for (int r = 0; r < NROW; ++r) {
      int s = r % 6;
      z[r] += br + p[s] + wl + ((s < 2) ? hp0 : hp1);
    }
  }
  ln24_norm(z, redbuf, ln_g[tid], ln_b[tid], tid);
  #pragma unroll
  for (int r = 0; r < NROW; ++r)
    *(__hip_bfloat16*)(hsb + swz(r, tid*2)) = f2bf(z[r]);

  // ---------------- res (bt<64 only), packed bf16 pairs --------------------
  unsigned resp[12];
  #pragma unroll
  for (int k = 0; k < 12; ++k) resp[k] = 0u;
  if (bt < 64) {
    __syncthreads();   // embed xbuf reads done (uniform branch)
    for (int idx = tid; idx < TB*6*128; idx += 256) {
      int tt = idx / 768, rem = idx % 768;
      int s = rem >> 7, f = rem & 127;
      int t = bt*TB + tt;
      xbuf[tt*6+s][f] = x[(t*128 + s)*128 + f];
    }
    __syncthreads();
    float resv[NROW];
    float brr = b_res[tid];
    #pragma unroll
    for (int r = 0; r < NROW; ++r) resv[r] = brr;
    #pragma unroll 2
    for (int f4 = 0; f4 < 32; ++f4) {
      float w0 = W_res[(f4*4+0)*256 + tid];
      float w1 = W_res[(f4*4+1)*256 + tid];
      float w2 = W_res[(f4*4+2)*256 + tid];
      float w3 = W_res[(f4*4+3)*256 + tid];
      #pragma unroll
      for (int r = 0; r < NROW; ++r) {
        float4 xv = *(const float4*)(&xbuf[r][f4*4]);
        resv[r] += xv.x*w0 + xv.y*w1 + xv.z*w2 + xv.w*w3;
      }
    }
    #pragma unroll
    for (int k = 0; k < 12; ++k) {
      unsigned lo = __float_as_uint(resv[2*k])   >> 16;
      unsigned hi = __float_as_uint(resv[2*k+1]) & 0xffff0000u;
      resp[k] = hi | lo;
    }
  }

  // first layer's QKV fragments: issue now, covered by LN/epilogue above
  bfv8 preQ[8];
  preload8(wf + OWQ + (unsigned)wid*8u*512u + lane*8, preQ);

  // ---------------- layers ----------------
  #pragma unroll 1
  for (int l = 0; l < 4; ++l) {
    const __hip_bfloat16* WQf = wf + OWQ + (unsigned)l*196608u;
    const __hip_bfloat16* WOf = wf + OWO + (unsigned)l*65536u;
    const __hip_bfloat16* W1f = wf + OW1 + (unsigned)l*262144u;
    const __hip_bfloat16* W2f = wf + OW2 + (unsigned)l*262144u;

    float n1gv = n1g[l*256 + tid], n1bv = n1b[l*256 + tid];
    float n2gv = n2g[l*256 + tid], n2bv = n2b[l*256 + tid];
    float bov  = bo[l*256 + tid],  b2v  = b2[l*256 + tid];

    float bb[12];
    #pragma unroll
    for (int i = 0; i < 12; ++i) bb[i] = bqkv[l*768 + (wid + i*4)*16 + l15];

    __syncthreads();   // hsb ready; q/k/v regions free

    // ---- QKV (N=768, K=256): epi routes n-tiles to q/k/v buffers ----
    {
      bfv8 a0[8], a1[8];
      #pragma unroll
      for (int ks = 0; ks < 8; ++ks) {
        a0[ks] = *(const bfv8*)(hsb + swz(l15,      ks*64 + l4*16));
        a1[ks] = *(const bfv8*)(hsb + swz(16 + l15, ks*64 + l4*16));
      }
      gemm_sec<12, 8>(WQf + (unsigned)wid*8u*512u + lane*8, preQ, a0, a1,
        [&](int i, f32x4 c0, f32x4 c1) {
          char* qb = smem + O_R1 + (i >> 2)*12288;     // q / k / v
          int col = (wid + (i & 3)*4)*16 + l15;
          float bbv = bb[i];
          #pragma unroll
          for (int j = 0; j < 4; ++j) {
            *(__hip_bfloat16*)(qb + swz(l4*4 + j, col*2)) = f2bf(c0[j] + bbv);
            int r1 = 16 + l4*4 + j;
            if (r1 < NROW)
              *(__hip_bfloat16*)(qb + swz(r1, col*2)) = f2bf(c1[j] + bbv);
          }
        });
    }
    __syncthreads();

    // ---- warp-local attention: wave wid owns token wid (rows 6w..6w+5) ----
    bfv8 preB[8];
    preload8(WOf + (unsigned)wid*8u*512u + lane*8, preB);  // Wo prefetch
    {
      int hh = lane >> 3, qq = lane & 7;
      if (qq < 6) {
        int row = wid*6 + qq;
        float qf[32];
        #pragma unroll
        for (int p4 = 0; p4 < 4; ++p4) {
          bfv8 qv = *(const bfv8*)(uQ + swz(row, (hh*32 + p4*8)*2));
          #pragma unroll
          for (int j = 0; j < 8; ++j) qf[p4*8+j] = bfs2f(qv[j]);
        }
        float a[6];
        float mx = -1e30f;
        #pragma unroll
        for (int sp = 0; sp < 6; ++sp) {
          float s = 0.f;
          #pragma unroll
          for (int p4 = 0; p4 < 4; ++p4) {
            bfv8 kv = *(const bfv8*)(uK + swz(wid*6 + sp, (hh*32 + p4*8)*2));
            #pragma unroll
            for (int j = 0; j < 8; ++j) s += qf[p4*8+j] * bfs2f(kv[j]);
          }
          a[sp] = s * 0.17677669529663687f;   // 1/sqrt(32)
          mx = fmaxf(mx, a[sp]);
        }
        float sum = 0.f;
        #pragma unroll
        for (int sp = 0; sp < 6; ++sp) { a[sp] = __expf(a[sp] - mx); sum += a[sp]; }
        float inv = 1.f / sum;
        #pragma unroll
        for (int sp = 0; sp < 6; ++sp) a[sp] *= inv;
        #pragma unroll
        for (int cb = 0; cb < 4; ++cb) {
          float acc[8];
          #pragma unroll
          for (int j = 0; j < 8; ++j) acc[j] = 0.f;
          #pragma unroll
          for (int sp = 0; sp < 6; ++sp) {
            bfv8 vv = *(const bfv8*)(uV + swz(wid*6 + sp, (hh*32 + cb*8)*2));
            #pragma unroll
            for (int j = 0; j < 8; ++j) acc[j] += a[sp] * bfs2f(vv[j]);
          }
          __align__(16) __hip_bfloat16 ob[8];
          #pragma unroll
          for (int j = 0; j < 8; ++j) ob[j] = f2bf(acc[j]);
          *(uint4*)(uQ + swz(row, (hh*32 + cb*8)*2)) = *(const uint4*)ob;  // o over q
        }
      }
    }
    __syncthreads();   // o visible; k/v dead

    // ---- attn = o @ Wo -> fbuf fp32 (over k+v regions) ----
    {
      bfv8 a0[8], a1[8];
      #pragma unroll
      for (int ks = 0; ks < 8; ++ks) {
        a0[ks] = *(const bfv8*)(uQ + swz(l15,      ks*64 + l4*16));
        a1[ks] = *(const bfv8*)(uQ + swz(16 + l15, ks*64 + l4*16));
      }
      gemm_sec<4, 8>(WOf + (unsigned)wid*8u*512u + lane*8, preB, a0, a1,
        [&](int i, f32x4 c0, f32x4 c1) {
          int col = (wid + i*4)*16 + l15;
          #pragma unroll
          for (int j = 0; j < 4; ++j) {
            fbuf[l4*4 + j][col] = c0[j];
            int r1 = 16 + l4*4 + j;
            if (r1 < NROW) fbuf[r1][col] = c1[j];
          }
        });
    }
    __syncthreads();   // fbuf visible

    // ---- z = h + attn + res ; LN1 ; -> hsb ----
    bfv8 w1b[8];
    preload8(W1f + (unsigned)wid*8u*512u + lane*8, w1b);  // W1 ch0 prefetch
    #pragma unroll
    for (int r = 0; r < NROW; ++r)
      z[r] += unpk(resp[r >> 1], r & 1) + fbuf[r][tid] + bov;
    ln24_norm(z, redbuf, n1gv, n1bv, tid);
    #pragma unroll
    for (int r = 0; r < NROW; ++r)
      *(__hip_bfloat16*)(hsb + swz(r, tid*2)) = f2bf(z[r]);
    __syncthreads();   // hsb ready; gelu buffers (R1/R2) free

    // ---- FFN: 4 hidden chunks; gelu -> dbuf LDS; W2 accumulates in regs ----
    {
      bfv8 ah0[8], ah1[8];
      #pragma unroll
      for (int ks = 0; ks < 8; ++ks) {
        ah0[ks] = *(const bfv8*)(hsb + swz(l15,      ks*64 + l4*16));
        ah1[ks] = *(const bfv8*)(hsb + swz(16 + l15, ks*64 + l4*16));
      }
      f32x4 facc[8];
      #pragma unroll
      for (int k = 0; k < 8; ++k) facc[k] = (f32x4){0.f,0.f,0.f,0.f};

      #pragma unroll 1
      for (int ch = 0; ch < 4; ++ch) {
        char* gb = smem + O_R1 + (ch & 1)*12288;
        float bb1[4];
        #pragma unroll
        for (int i = 0; i < 4; ++i) bb1[i] = b1[l*1024 + ch*256 + (wid + i*4)*16 + l15];

        gemm_sec<4, 8>(W1f + (unsigned)(ch*128 + wid*8)*512u + lane*8, w1b, ah0, ah1,
          [&](int i, f32x4 c0, f32x4 c1) {
            int col2 = ((wid + i*4)*16 + l15)*2;
            #pragma unroll
            for (int j = 0; j < 4; ++j) {
              *(__hip_bfloat16*)(gb + swz(l4*4 + j, col2)) = f2bf(gelu_f(c0[j] + bb1[i]));
              int r1 = 16 + l4*4 + j;
              if (r1 < NROW)
                *(__hip_bfloat16*)(gb + swz(r1, col2)) = f2bf(gelu_f(c1[j] + bb1[i]));
            }
          });
        bfv8 w2b[8];
        preload8(W2f + (unsigned)(wid*32 + ch*8)*512u + lane*8, w2b);  // W2 prefetch
        __syncthreads();   // gelu chunk visible

        bfv8 g0[8], g1[8];
        #pragma unroll
        for (int ks = 0; ks < 8; ++ks) {
          g0[ks] = *(const bfv8*)(gb + swz(l15,      ks*64 + l4*16));
          g1[ks] = *(const bfv8*)(gb + swz(16 + l15, ks*64 + l4*16));
        }
        if (ch < 3) preload8(W1f + (unsigned)((ch+1)*128 + wid*8)*512u + lane*8, w1b);
        gemm_sec<4, 32>(W2f + (unsigned)(wid*32 + ch*8)*512u + lane*8, w2b, g0, g1,
          [&](int i, f32x4 c0, f32x4 c1) {
            facc[2*i]   += c0;
            facc[2*i+1] += c1;
          });
      }
      __syncthreads();   // last gelu reads done -> fbuf region writable
      #pragma unroll
      for (int i = 0; i < 4; ++i) {
        int col = (wid + i*4)*16 + l15;
        #pragma unroll
        for (int j = 0; j < 4; ++j) {
          fbuf[l4*4 + j][col] = facc[2*i][j];
          int r1 = 16 + l4*4 + j;
          if (r1 < NROW) fbuf[r1][col] = facc[2*i+1][j];
        }
      }
    }
    __syncthreads();   // fbuf visible

    // ---- z = h1 + ff + res ; LN2 ; -> hsb ----
    if (l < 3)
      preload8(wf + OWQ + (unsigned)(l+1)*196608u + (unsigned)wid*8u*512u + lane*8, preQ);
    #pragma unroll
    for (int r = 0; r < NROW; ++r)
      z[r] += unpk(resp[r >> 1], r & 1) + fbuf[r][tid] + b2v;
    ln24_norm(z, redbuf, n2gv, n2bv, tid);
    #pragma unroll
    for (int r = 0; r < NROW; ++r)
      *(__hip_bfloat16*)(hsb + swz(r, tid*2)) = f2bf(z[r]);
  }

  // ---------------- output: h[:,0] ----------------
  #pragma unroll
  for (int tt = 0; tt < TB; ++tt)
    out[(bt*TB + tt)*256 + tid] = z[tt*6];
}

// ---------------------------------------------------------------------------
// Fallback (pure-VALU, round-2 proven) if ws too small for weight staging.
__global__ __launch_bounds__(256, 2) void gb_fused_fallback(
    const float* __restrict__ x,
    const float* __restrict__ W_raw, const float* __restrict__ b_raw,
    const float* __restrict__ wl_emb, const float* __restrict__ pos_emb,
    const float* __restrict__ hop_emb,
    const float* __restrict__ ln_g, const float* __restrict__ ln_b,
    const float* __restrict__ Wqkv, const float* __restrict__ bqkv,
    const float* __restrict__ Wo,   const float* __restrict__ bo,
    const float* __restrict__ n1g,  const float* __restrict__ n1b,
    const float* __restrict__ W1,   const float* __restrict__ b1,
    const float* __restrict__ W2,   const float* __restrict__ b2,
    const float* __restrict__ n2g,  const float* __restrict__ n2b,
    const float* __restrict__ W_res, const float* __restrict__ b_res,
    float* __restrict__ out)
{
  __shared__ float hs[NROW][256];
  __shared__ __align__(16) char bufraw[NROW*768*2];
  __shared__ float attw[8][NROW][8];
  __shared__ float redbuf[192];

  __hip_bfloat16 (*qkvs)[768] = (__hip_bfloat16 (*)[768])bufraw;
  float (*fbuf)[256] = (float (*)[256])bufraw;
  float (*xbuf)[128] = (float (*)[128])bufraw;

  const int tid = threadIdx.x;
  const int bt  = blockIdx.x;

  for (int idx = tid; idx < TB*6*128; idx += 256) {
    int tt = idx / 768, rem = idx % 768;
    int s = rem >> 7, f = rem & 127;
    int t = bt*TB + tt, g = t >> 7, i = t & 127;
    int node;
    if (s < 2) node = i;
    else { int j = s - 2; node = (j < i) ? j : (j + 1); }
    xbuf[tt*6+s][f] = x[(g*128 + node)*128 + f];
  }
  __syncthreads();

  float z[NROW];
  {
    #pragma unroll
    for (int r = 0; r < NROW; ++r) z[r] = 0.f;
    #pragma unroll 4
    for (int f = 0; f < 128; ++f) {
      float w = W_raw[f*256 + tid];
      #pragma unroll
      for (int r = 0; r < NROW; ++r) z[r] += xbuf[r][f] * w;
    }
    float br  = b_raw[tid];
    float wl  = wl_emb[tid];
    float hp0 = hop_emb[5*256 + tid];
    float hp1 = hop_emb[511*256 + tid];
    float p[6];
    #pragma unroll
    for (int s = 0; s < 6; ++s) p[s] = pos_emb[s*256 + tid];
    #pragma unroll
    for (int r = 0; r < NROW; ++r) {
      int s = r % 6;
      z[r] += br + p[s] + wl + ((s < 2) ? hp0 : hp1);
    }
  }
  ln24_norm(z, redbuf, ln_g[tid], ln_b[tid], tid);
  #pragma unroll
  for (int r = 0; r < NROW; ++r) hs[r][tid] = z[r];

  float resv[NROW];
  #pragma unroll
  for (int r = 0; r < NROW; ++r) resv[r] = 0.f;
  if (bt < 64) {
    __syncthreads();
    for (int idx = tid; idx < TB*6*128; idx += 256) {
      int tt = idx / 768, rem = idx % 768;
      int s = rem >> 7, f = rem & 127;
      int t = bt*TB + tt;
      xbuf[tt*6+s][f] = x[(t*128 + s)*128 + f];
    }
    __syncthreads();
    #pragma unroll 4
    for (int f = 0; f < 128; ++f) {
      float w = W_res[f*256 + tid];
      #pragma unroll
      for (int r = 0; r < NROW; ++r) resv[r] += xbuf[r][f] * w;
    }
    float brr = b_res[tid];
    #pragma unroll
    for (int r = 0; r < NROW; ++r) resv[r] += brr;
  }

  for (int l = 0; l < 4; ++l) {
    const float* Wqkv_l = Wqkv + l*196608;
    const float* bqkv_l = bqkv + l*768;
    const float* Wo_l   = Wo   + l*65536;
    const float* bo_l   = bo   + l*256;
    const float* W1_l   = W1   + l*262144;
    const float* b1_l   = b1   + l*1024;
    const float* W2_l   = W2   + l*262144;
    const float* b2_l   = b2   + l*256;

    __syncthreads();

    for (int cg = 0; cg < 3; ++cg) {
      int col = cg*256 + tid;
      float acc[NROW];
      #pragma unroll
      for (int r = 0; r < NROW; ++r) acc[r] = 0.f;
      #pragma unroll 4
      for (int kk = 0; kk < 256; ++kk) {
        float w = Wqkv_l[kk*768 + col];
        #pragma unroll
        for (int r = 0; r < NROW; ++r) acc[r] += hs[r][kk] * w;
      }
      float bbv = bqkv_l[col];
      #pragma unroll
      for (int r = 0; r < NROW; ++r) qkvs[r][col] = f2bf(acc[r] + bbv);
    }
    __syncthreads();

    #pragma unroll 1
    for (int it = 0; it < 5; ++it) {
      int idx = it*256 + tid;
      if (idx < 1152) {
        int hh = idx / 144, rem = idx % 144;
        int r = rem / 6, sp = rem % 6;
        int tt6 = (r / 6) * 6;
        float sc = 0.f;
        #pragma unroll
        for (int c = 0; c < 32; ++c)
          sc += bf2f(qkvs[r][hh*32 + c]) * bf2f(qkvs[tt6 + sp][256 + hh*32 + c]);
        attw[hh][r][sp] = sc * 0.17677669529663687f;
      }
    }
    __syncthreads();

    if (tid < 192) {
      int hh = tid / 24, r = tid % 24;
      float mx = attw[hh][r][0];
      #pragma unroll
      for (int sp = 1; sp < 6; ++sp) mx = fmaxf(mx, attw[hh][r][sp]);
      float e[6], sum = 0.f;
      #pragma unroll
      for (int sp = 0; sp < 6; ++sp) { e[sp] = expf(attw[hh][r][sp] - mx); sum += e[sp]; }
      float inv = 1.f / sum;
      #pragma unroll
      for (int sp = 0; sp < 6; ++sp) attw[hh][r][sp] = e[sp] * inv;
    }
    __syncthreads();

    float oreg[NROW];
    {
      int hh = tid >> 5, c = tid & 31;
      #pragma unroll
      for (int r = 0; r < NROW; ++r) {
        int tt6 = (r / 6) * 6;
        float o = 0.f;
        #pragma unroll
        for (int sp = 0; sp < 6; ++sp)
          o += attw[hh][r][sp] * bf2f(qkvs[tt6 + sp][512 + hh*32 + c]);
        oreg[r] = o;
      }
    }
    __syncthreads();
    #pragma unroll
    for (int r = 0; r < NROW; ++r) fbuf[r][tid] = oreg[r];
    __syncthreads();

    {
      float bod = bo_l[tid];
      float zz[NROW];
      #pragma unroll
      for (int r = 0; r < NROW; ++r) zz[r] = bod;
      #pragma unroll 4
      for (int kk = 0; kk < 256; ++kk) {
        float w = Wo_l[kk*256 + tid];
        #pragma unroll
        for (int r = 0; r < NROW; ++r) zz[r] += fbuf[r][kk] * w;
      }
      #pragma unroll
      for (int r = 0; r < NROW; ++r) z[r] += zz[r] + resv[r];
    }
    ln24_norm(z, redbuf, n1g[l*256 + tid], n1b[l*256 + tid], tid);
    #pragma unroll
    for (int r = 0; r < NROW; ++r) hs[r][tid] = z[r];
    __syncthreads();

    float ff[NROW];
    {
      float b2d = b2_l[tid];
      #pragma unroll
      for (int r = 0; r < NROW; ++r) ff[r] = b2d;
    }
    for (int ch = 0; ch < 4; ++ch) {
      int j = ch*256 + tid;
      float gvv[NROW];
      float b1j = b1_l[j];
      #pragma unroll
      for (int r = 0; r < NROW; ++r) gvv[r] = b1j;
      #pragma unroll 4
      for (int kk = 0; kk < 256; ++kk) {
        float w = W1_l[kk*1024 + j];
        #pragma unroll
        for (int r = 0; r < NROW; ++r) gvv[r] += hs[r][kk] * w;
      }
      __syncthreads();
      #pragma unroll
      for (int r = 0; r < NROW; ++r) fbuf[r][tid] = gelu_f(gvv[r]);
      __syncthreads();
      #pragma unroll 4
      for (int kk = 0; kk < 256; ++kk) {
        float w = W2_l[(ch*256 + kk)*256 + tid];
        #pragma unroll
        for (int r = 0; r < NROW; ++r) ff[r] += fbuf[r][kk] * w;
      }
    }
    #pragma unroll
    for (int r = 0; r < NROW; ++r) z[r] += ff[r] + resv[r];
    ln24_norm(z, redbuf, n2g[l*256 + tid], n2b[l*256 + tid], tid);
    #pragma unroll
    for (int r = 0; r < NROW; ++r) hs[r][tid] = z[r];
  }

  __syncthreads();
  #pragma unroll
  for (int tt = 0; tt < TB; ++tt)
    out[(bt*TB + tt)*256 + tid] = hs[tt*6][tid];
}

extern "C" void kernel_launch(void* const* d_in, const int* in_sizes, int n_in,
                              void* d_out, int out_size, void* d_ws, size_t ws_size,
                              hipStream_t stream) {
  (void)in_sizes; (void)n_in; (void)out_size;
  const float* x      = (const float*)d_in[0];
  const float* W_raw  = (const float*)d_in[1];
  const float* b_raw  = (const float*)d_in[2];
  const float* wl_emb = (const float*)d_in[3];
  const float* pos_emb= (const float*)d_in[4];
  const float* hop_emb= (const float*)d_in[5];
  const float* ln_g   = (const float*)d_in[6];
  const float* ln_b   = (const float*)d_in[7];
  const float* Wqkv   = (const float*)d_in[8];
  const float* bqkv   = (const float*)d_in[9];
  const float* Wo     = (const float*)d_in[10];
  const float* bo     = (const float*)d_in[11];
  const float* n1g    = (const float*)d_in[12];
  const float* n1b    = (const float*)d_in[13];
  const float* W1     = (const float*)d_in[14];
  const float* b1     = (const float*)d_in[15];
  const float* W2     = (const float*)d_in[16];
  const float* b2     = (const float*)d_in[17];
  const float* n2g    = (const float*)d_in[18];
  const float* n2b    = (const float*)d_in[19];
  const float* W_res  = (const float*)d_in[20];
  const float* b_res  = (const float*)d_in[21];

  if (ws_size >= (size_t)WS_ELEMS * 2) {
    __hip_bfloat16* wsb = (__hip_bfloat16*)d_ws;
    gb_prep_kernel<<<1536, 256, 0, stream>>>(Wqkv, Wo, W1, W2, wsb);
    gb_mfma_kernel<<<8192, 256, 0, stream>>>(
        x, W_raw, b_raw, wl_emb, pos_emb, hop_emb, ln_g, ln_b,
        bqkv, bo, n1g, n1b, b1, b2, n2g, n2b, W_res, b_res,
        wsb, (float*)d_out);
  } else {
    gb_fused_fallback<<<8192, 256, 0, stream>>>(
        x, W_raw, b_raw, wl_emb, pos_emb, hop_emb, ln_g, ln_b,
        Wqkv, bqkv, Wo, bo, n1g, n1b, W1, b1, W2, b2, n2g, n2b,
        W_res, b_res, (float*)d_out);
  }
}

// Round 6
// 7468.145 us; speedup vs baseline: 1.6633x; 1.6633x over previous
//
#include <hip/hip_runtime.h>
#include <hip/hip_bf16.h>

// GraphBertEncoder: T=32768 tokens, S=6, D=256, H=8 (hd=32), L=4.
// Round 6: round-4 structure (proven 6.41ms) + (1) waves_per_eu(2,2) to stop
// the allocator squeezing to 128 VGPR (LDS caps occupancy at 2 waves/EU
// anyway), (2) depth-3 B-fragment prefetch (QKV/Wo/W1; W2 depth-2), (3)
// s_setprio around MFMA clusters.

#define TB 4
#define NROW 24

typedef float f32x4 __attribute__((ext_vector_type(4)));
typedef short bfv8  __attribute__((ext_vector_type(8)));   // 8 bf16 = 4 VGPR

__device__ __forceinline__ float bf2f(__hip_bfloat16 v) { return __bfloat162float(v); }
__device__ __forceinline__ __hip_bfloat16 f2bf(float v) { return __float2bfloat16(v); }
__device__ __forceinline__ float bfs2f(short s) { return __uint_as_float(((unsigned)(unsigned short)s) << 16); }
// swizzled byte offset into a [32][256] bf16 tile (row stride 512B)
__device__ __forceinline__ int swz(int row, int cb) { return row*512 + (cb ^ ((row & 7) << 4)); }
__device__ __forceinline__ float gelu_f(float v) { return 0.5f*v*(1.f + erff(v*0.70710678118654752f)); }
__device__ __forceinline__ float unpk(unsigned p, int hi) {
  return __uint_as_float(hi ? (p & 0xffff0000u) : (p << 16));
}

// ws fragment-layout offsets (bf16 elements)
#define OWQ 0u
#define OWO 786432u
#define OW1 1048576u
#define OW2 2097152u
#define WS_ELEMS 3145728u   // *2B = 6291456 bytes

// ---------------------------------------------------------------------------
// prep: fp32 weights -> bf16 B-fragment-linear in ws.
// fragment f of a KxN weight: lane l, j holds W[ks*32+(l>>4)*8+j][nt*16+(l&15)]
// stored at base + f*512 + l*8 + j, f = nt*(K/32) + ks.
__global__ __launch_bounds__(256) void gb_prep_kernel(
    const float* __restrict__ Wqkv, const float* __restrict__ Wo,
    const float* __restrict__ W1,   const float* __restrict__ W2,
    __hip_bfloat16* __restrict__ ws)
{
  int fg   = blockIdx.x * 4 + (threadIdx.x >> 6);   // 0..6143
  int lane = threadIdx.x & 63;
  int layer = fg / 1536, r = fg % 1536;
  const float* src; int K, N, fl; unsigned dstbase;
  if (r < 384)       { src = Wqkv + layer*196608; K = 256;  N = 768;  fl = r;       dstbase = OWQ + layer*196608u; }
  else if (r < 512)  { src = Wo   + layer*65536;  K = 256;  N = 256;  fl = r - 384; dstbase = OWO + layer*65536u;  }
  else if (r < 1024) { src = W1   + layer*262144; K = 256;  N = 1024; fl = r - 512; dstbase = OW1 + layer*262144u; }
  else               { src = W2   + layer*262144; K = 1024; N = 256;  fl = r - 1024;dstbase = OW2 + layer*262144u; }
  int nk = K >> 5;
  int nt = fl / nk, ks = fl % nk;
  int n  = nt*16 + (lane & 15);
  int k0 = ks*32 + (lane >> 4)*8;
  __align__(16) __hip_bfloat16 tmp[8];
  #pragma unroll
  for (int j = 0; j < 8; ++j) tmp[j] = f2bf(src[(size_t)(k0 + j)*N + n]);
  *(uint4*)(ws + dstbase + (unsigned)fl*512u + lane*8) = *(const uint4*)tmp;
}

// ---------------------------------------------------------------------------
__device__ __forceinline__ void preload8(const __hip_bfloat16* __restrict__ p, bfv8 (&b)[8]) {
  #pragma unroll
  for (int k = 0; k < 8; ++k) b[k] = *(const bfv8*)(p + k*512);
}

// one-pass LayerNorm over 256 columns for 24 rows (thread owns column tid).
__device__ __forceinline__ void ln24_norm(float* z, float* redbuf, float g, float b, int tid) {
  const int lane = tid & 63, wid = tid >> 6;
  float s1[NROW], s2[NROW];
  #pragma unroll
  for (int r = 0; r < NROW; ++r) { float v = z[r]; s1[r] = v; s2[r] = v*v; }
  #pragma unroll
  for (int off = 32; off; off >>= 1) {
    #pragma unroll
    for (int r = 0; r < NROW; ++r) {
      s1[r] += __shfl_down(s1[r], off, 64);
      s2[r] += __shfl_down(s2[r], off, 64);
    }
  }
  if (lane == 0) {
    #pragma unroll
    for (int r = 0; r < NROW; ++r) { redbuf[wid*48 + r] = s1[r]; redbuf[wid*48 + 24 + r] = s2[r]; }
  }
  __syncthreads();
  #pragma unroll
  for (int r = 0; r < NROW; ++r) {
    float S1 = redbuf[r] + redbuf[48+r] + redbuf[96+r] + redbuf[144+r];
    float S2 = redbuf[24+r] + redbuf[72+r] + redbuf[120+r] + redbuf[168+r];
    float m  = S1 * (1.0f/256.0f);
    float var = S2 * (1.0f/256.0f) - m*m;
    float iv = rsqrtf(var + 1e-5f);
    z[r] = (z[r] - m) * iv * g + b;
  }
  __syncthreads();
}

// ---------------------------------------------------------------------------
// GEMM section: per wave, NTI n-tiles (nt = wid + 4*i), K=256 (8 fragments).
// DEPTH-deep rotating B prefetch (2-ahead at DEPTH=3); 4 independent MFMA
// chains; s_setprio(1) around each MFMA cluster. epi(i, c0, c1).
template<int NTI, int NKTOT, int DEPTH, class Epi>
__device__ __forceinline__ void gemm_sec(const __hip_bfloat16* __restrict__ p,
                                         const bfv8 (&a0)[8], const bfv8 (&a1)[8],
                                         Epi epi)
{
  const unsigned ST = 4u*(unsigned)NKTOT*512u;
  bfv8 B[DEPTH][8];
  preload8(p, B[0]);
  if (DEPTH > 2 && NTI > 1) preload8(p + ST, B[1 % DEPTH]);
  #pragma unroll
  for (int i = 0; i < NTI; ++i) {
    if (DEPTH > 2) {
      if (i + 2 < NTI) preload8(p + (unsigned)(i+2)*ST, B[(i+2) % DEPTH]);
    } else {
      if (i + 1 < NTI) preload8(p + (unsigned)(i+1)*ST, B[(i+1) % DEPTH]);
    }
    __builtin_amdgcn_s_setprio(1);
    f32x4 c0a = {0,0,0,0}, c0b = {0,0,0,0}, c1a = {0,0,0,0}, c1b = {0,0,0,0};
    #pragma unroll
    for (int k = 0; k < 8; k += 2) {
      c0a = __builtin_amdgcn_mfma_f32_16x16x32_bf16(a0[k],   B[i % DEPTH][k],   c0a, 0,0,0);
      c1a = __builtin_amdgcn_mfma_f32_16x16x32_bf16(a1[k],   B[i % DEPTH][k],   c1a, 0,0,0);
      c0b = __builtin_amdgcn_mfma_f32_16x16x32_bf16(a0[k+1], B[i % DEPTH][k+1], c0b, 0,0,0);
      c1b = __builtin_amdgcn_mfma_f32_16x16x32_bf16(a1[k+1], B[i % DEPTH][k+1], c1b, 0,0,0);
    }
    __builtin_amdgcn_s_setprio(0);
    epi(i, c0a + c0b, c1a + c1b);
  }
}

// ---------------------------------------------------------------------------
__global__ __launch_bounds__(256)
__attribute__((amdgpu_waves_per_eu(2, 2)))
void gb_mfma_kernel(
    const float* __restrict__ x,
    const float* __restrict__ W_raw, const float* __restrict__ b_raw,
    const float* __restrict__ wl_emb, const float* __restrict__ pos_emb,
    const float* __restrict__ hop_emb,
    const float* __restrict__ ln_g, const float* __restrict__ ln_b,
    const float* __restrict__ bqkv, const float* __restrict__ bo,
    const float* __restrict__ n1g,  const float* __restrict__ n1b,
    const float* __restrict__ b1,   const float* __restrict__ b2,
    const float* __restrict__ n2g,  const float* __restrict__ n2b,
    const float* __restrict__ W_res, const float* __restrict__ b_res,
    const __hip_bfloat16* __restrict__ wf,
    float* __restrict__ out)
{
  // LDS: hsb 16K | uA 37248 (xbuf fp32 | qkvs bf16 | fbuf fp32 | gelu dbuf 2x16K)
  //      uB 16K (o swz bf16) | attw 4608 | redbuf 768  => 75392 B (2 blocks/CU)
  __shared__ __align__(16) char smem[75392];
  char* hsb = smem;                              // [32][512B] swz bf16
  char* uA  = smem + 16384;
  char* uB  = smem + 53632;                      // [32][512B] swz bf16
  float (*attw)[24][6] = (float (*)[24][6])(smem + 70016);
  float* redbuf = (float*)(smem + 74624);

  __hip_bfloat16 (*qkvs)[776] = (__hip_bfloat16 (*)[776])uA;
  float (*fbuf)[264] = (float (*)[264])uA;
  float (*xbuf)[128] = (float (*)[128])uA;

  const int tid  = threadIdx.x;
  const int bt   = blockIdx.x;
  const int lane = tid & 63, wid = tid >> 6;
  const int l15  = lane & 15, l4 = lane >> 4;

  // zero rows 24-31 of hsb and uB once (A-fragments read rows 16..31)
  {
    uint4 zz = {0u,0u,0u,0u};
    *(uint4*)(hsb + 24*512 + tid*16) = zz;
    *(uint4*)(uB  + 24*512 + tid*16) = zz;
  }

  // ---------------- Embedding: stage sub_x rows (fp32, idx mapping) --------
  for (int idx = tid; idx < TB*6*128; idx += 256) {
    int tt = idx / 768, rem = idx % 768;
    int s = rem >> 7, f = rem & 127;
    int t = bt*TB + tt, g = t >> 7, i = t & 127;
    int node;
    if (s < 2) node = i;
    else { int j = s - 2; node = (j < i) ? j : (j + 1); }
    xbuf[tt*6+s][f] = x[(g*128 + node)*128 + f];
  }
  __syncthreads();

  float z[NROW];
  {
    #pragma unroll
    for (int r = 0; r < NROW; ++r) z[r] = 0.f;
    #pragma unroll 2
    for (int f4 = 0; f4 < 32; ++f4) {
      float w0 = W_raw[(f4*4+0)*256 + tid];
      float w1 = W_raw[(f4*4+1)*256 + tid];
      float w2 = W_raw[(f4*4+2)*256 + tid];
      float w3 = W_raw[(f4*4+3)*256 + tid];
      #pragma unroll
      for (int r = 0; r < NROW; ++r) {
        float4 xv = *(const float4*)(&xbuf[r][f4*4]);
        z[r] += xv.x*w0 + xv.y*w1 + xv.z*w2 + xv.w*w3;
      }
    }
    float br  = b_raw[tid];
    float wl  = wl_emb[tid];
    float hp0 = hop_emb[5*256 + tid];
    float hp1 = hop_emb[511*256 + tid];
    float p[6];
    #pragma unroll
    for (int s = 0; s < 6; ++s) p[s] = pos_emb[s*256 + tid];
    #pragma unroll
    for (int r = 0; r < NROW; ++r) {
      int s = r % 6;
      z[r] += br + p[s] + wl + ((s < 2) ? hp0 : hp1);
    }
  }
  ln24_norm(z, redbuf, ln_g[tid], ln_b[tid], tid);
  #pragma unroll
  for (int r = 0; r < NROW; ++r)
    *(__hip_bfloat16*)(hsb + swz(r, tid*2)) = f2bf(z[r]);

  // ---------------- res (bt<64 only), packed bf16 pairs --------------------
  unsigned resp[12];
  #pragma unroll
  for (int k = 0; k < 12; ++k) resp[k] = 0u;
  if (bt < 64) {
    __syncthreads();   // embed xbuf reads done (uniform branch)
    for (int idx = tid; idx < TB*6*128; idx += 256) {
      int tt = idx / 768, rem = idx % 768;
      int s = rem >> 7, f = rem & 127;
      int t = bt*TB + tt;
      xbuf[tt*6+s][f] = x[(t*128 + s)*128 + f];
    }
    __syncthreads();
    float resv[NROW];
    float brr = b_res[tid];
    #pragma unroll
    for (int r = 0; r < NROW; ++r) resv[r] = brr;
    #pragma unroll 2
    for (int f4 = 0; f4 < 32; ++f4) {
      float w0 = W_res[(f4*4+0)*256 + tid];
      float w1 = W_res[(f4*4+1)*256 + tid];
      float w2 = W_res[(f4*4+2)*256 + tid];
      float w3 = W_res[(f4*4+3)*256 + tid];
      #pragma unroll
      for (int r = 0; r < NROW; ++r) {
        float4 xv = *(const float4*)(&xbuf[r][f4*4]);
        resv[r] += xv.x*w0 + xv.y*w1 + xv.z*w2 + xv.w*w3;
      }
    }
    #pragma unroll
    for (int k = 0; k < 12; ++k) {
      unsigned lo = __float_as_uint(resv[2*k])   >> 16;
      unsigned hi = __float_as_uint(resv[2*k+1]) & 0xffff0000u;
      resp[k] = hi | lo;
    }
  }

  // ---------------- layers ----------------
  #pragma unroll 1
  for (int l = 0; l < 4; ++l) {
    const __hip_bfloat16* WQf = wf + OWQ + (unsigned)l*196608u;
    const __hip_bfloat16* WOf = wf + OWO + (unsigned)l*65536u;
    const __hip_bfloat16* W1f = wf + OW1 + (unsigned)l*262144u;
    const __hip_bfloat16* W2f = wf + OW2 + (unsigned)l*262144u;

    float n1gv = n1g[l*256 + tid], n1bv = n1b[l*256 + tid];
    float n2gv = n2g[l*256 + tid], n2bv = n2b[l*256 + tid];
    float bov  = bo[l*256 + tid],  b2v  = b2[l*256 + tid];

    // qkv bias preload (12 n-tiles per wave)
    float bb[12];
    #pragma unroll
    for (int i = 0; i < 12; ++i) bb[i] = bqkv[l*768 + (wid + i*4)*16 + l15];

    __syncthreads();   // hsb ready; uA free for qkvs

    // ---- QKV (N=768, K=256) ----
    {
      bfv8 a0[8], a1[8];
      #pragma unroll
      for (int ks = 0; ks < 8; ++ks) {
        a0[ks] = *(const bfv8*)(hsb + swz(l15,      ks*64 + l4*16));
        a1[ks] = *(const bfv8*)(hsb + swz(16 + l15, ks*64 + l4*16));
      }
      gemm_sec<12, 8, 3>(WQf + (unsigned)wid*8u*512u + lane*8, a0, a1,
        [&](int i, f32x4 c0, f32x4 c1) {
          int col = (wid + i*4)*16 + l15;
          #pragma unroll
          for (int j = 0; j < 4; ++j) {
            qkvs[l4*4 + j][col] = f2bf(c0[j] + bb[i]);
            int r1 = 16 + l4*4 + j;
            if (r1 < NROW) qkvs[r1][col] = f2bf(c1[j] + bb[i]);
          }
        });
    }
    __syncthreads();

    // ---- scores + softmax fused (threads 0..191: (head, row)) ----
    if (tid < 192) {
      int hh = tid / 24, r = tid % 24;
      int tt6 = (r / 6) * 6;
      bfv8 qv[4];
      #pragma unroll
      for (int p4 = 0; p4 < 4; ++p4) qv[p4] = *(const bfv8*)(&qkvs[r][hh*32 + p4*8]);
      float sc[6];
      #pragma unroll
      for (int sp = 0; sp < 6; ++sp) {
        float s = 0.f;
        #pragma unroll
        for (int p4 = 0; p4 < 4; ++p4) {
          bfv8 kv = *(const bfv8*)(&qkvs[tt6 + sp][256 + hh*32 + p4*8]);
          #pragma unroll
          for (int j = 0; j < 8; ++j) s += bfs2f(qv[p4][j]) * bfs2f(kv[j]);
        }
        sc[sp] = s * 0.17677669529663687f;   // 1/sqrt(32)
      }
      float mx = sc[0];
      #pragma unroll
      for (int sp = 1; sp < 6; ++sp) mx = fmaxf(mx, sc[sp]);
      float sum = 0.f;
      #pragma unroll
      for (int sp = 0; sp < 6; ++sp) { sc[sp] = expf(sc[sp] - mx); sum += sc[sp]; }
      float inv = 1.f / sum;
      #pragma unroll
      for (int sp = 0; sp < 6; ++sp) attw[hh][r][sp] = sc[sp] * inv;
    }
    __syncthreads();

    // ---- o = a @ v -> uB (swz bf16). thread owns (head hh, col c) ----
    {
      int hh = tid >> 5, c = tid & 31;
      int col2 = (hh*32 + c)*2;
      #pragma unroll
      for (int tt = 0; tt < 4; ++tt) {
        float vv[6];
        #pragma unroll
        for (int sp = 0; sp < 6; ++sp) vv[sp] = bf2f(qkvs[tt*6 + sp][512 + hh*32 + c]);
        #pragma unroll
        for (int q = 0; q < 6; ++q) {
          float o = 0.f;
          #pragma unroll
          for (int sp = 0; sp < 6; ++sp) o += attw[hh][tt*6 + q][sp] * vv[sp];
          *(__hip_bfloat16*)(uB + swz(tt*6 + q, col2)) = f2bf(o);
        }
      }
    }
    __syncthreads();   // uB ready; qkvs dead -> fbuf writable

    // ---- attn = o @ Wo -> fbuf fp32 ----
    {
      bfv8 a0[8], a1[8];
      #pragma unroll
      for (int ks = 0; ks < 8; ++ks) {
        a0[ks] = *(const bfv8*)(uB + swz(l15,      ks*64 + l4*16));
        a1[ks] = *(const bfv8*)(uB + swz(16 + l15, ks*64 + l4*16));
      }
      gemm_sec<4, 8, 3>(WOf + (unsigned)wid*8u*512u + lane*8, a0, a1,
        [&](int i, f32x4 c0, f32x4 c1) {
          int col = (wid + i*4)*16 + l15;
          #pragma unroll
          for (int j = 0; j < 4; ++j) {
            fbuf[l4*4 + j][col] = c0[j];
            int r1 = 16 + l4*4 + j;
            if (r1 < NROW) fbuf[r1][col] = c1[j];
          }
        });
    }
    __syncthreads();

    // ---- z = h + attn + res ; LN1 ; -> hsb ----
    #pragma unroll
    for (int r = 0; r < NROW; ++r)
      z[r] += unpk(resp[r >> 1], r & 1) + fbuf[r][tid] + bov;
    ln24_norm(z, redbuf, n1gv, n1bv, tid);
    #pragma unroll
    for (int r = 0; r < NROW; ++r)
      *(__hip_bfloat16*)(hsb + swz(r, tid*2)) = f2bf(z[r]);
    // zero rows 24-31 of both gelu buffers (clobbered by qkvs earlier)
    {
      uint4 zz = {0u,0u,0u,0u};
      *(uint4*)(uA + 24*512 + tid*16) = zz;            // gb0 tail
      *(uint4*)(uA + 16384 + 24*512 + tid*16) = zz;    // gb1 tail
    }
    __syncthreads();   // hsb + gelu-tails ready

    // ---- FFN: 4 hidden chunks; gelu -> dbuf LDS; W2 accumulates in regs ----
    {
      bfv8 ah0[8], ah1[8];
      #pragma unroll
      for (int ks = 0; ks < 8; ++ks) {
        ah0[ks] = *(const bfv8*)(hsb + swz(l15,      ks*64 + l4*16));
        ah1[ks] = *(const bfv8*)(hsb + swz(16 + l15, ks*64 + l4*16));
      }
      f32x4 facc[8];
      #pragma unroll
      for (int k = 0; k < 8; ++k) facc[k] = (f32x4){0.f,0.f,0.f,0.f};

      #pragma unroll 1
      for (int ch = 0; ch < 4; ++ch) {
        char* gb = uA + (ch & 1)*16384;
        float bb1[4];
        #pragma unroll
        for (int i = 0; i < 4; ++i) bb1[i] = b1[l*1024 + ch*256 + (wid + i*4)*16 + l15];

        gemm_sec<4, 8, 3>(W1f + (unsigned)(ch*128 + wid*8)*512u + lane*8, ah0, ah1,
          [&](int i, f32x4 c0, f32x4 c1) {
            int col2 = ((wid + i*4)*16 + l15)*2;
            #pragma unroll
            for (int j = 0; j < 4; ++j) {
              *(__hip_bfloat16*)(gb + swz(l4*4 + j, col2)) = f2bf(gelu_f(c0[j] + bb1[i]));
              int r1 = 16 + l4*4 + j;
              if (r1 < NROW)
                *(__hip_bfloat16*)(gb + swz(r1, col2)) = f2bf(gelu_f(c1[j] + bb1[i]));
            }
          });
        __syncthreads();   // gelu chunk ready

        bfv8 g0[8], g1[8];
        #pragma unroll
        for (int ks = 0; ks < 8; ++ks) {
          g0[ks] = *(const bfv8*)(gb + swz(l15,      ks*64 + l4*16));
          g1[ks] = *(const bfv8*)(gb + swz(16 + l15, ks*64 + l4*16));
        }
        gemm_sec<4, 32, 2>(W2f + (unsigned)(wid*32 + ch*8)*512u + lane*8, g0, g1,
          [&](int i, f32x4 c0, f32x4 c1) {
            facc[2*i]   += c0;
            facc[2*i+1] += c1;
          });
      }
      __syncthreads();   // last gelu reads done -> fbuf region writable
      #pragma unroll
      for (int i = 0; i < 4; ++i) {
        int col = (wid + i*4)*16 + l15;
        #pragma unroll
        for (int j = 0; j < 4; ++j) {
          fbuf[l4*4 + j][col] = facc[2*i][j];
          int r1 = 16 + l4*4 + j;
          if (r1 < NROW) fbuf[r1][col] = facc[2*i+1][j];
        }
      }
    }
    __syncthreads();

    // ---- z = h1 + ff + res ; LN2 ; -> hsb ----
    #pragma unroll
    for (int r = 0; r < NROW; ++r)
      z[r] += unpk(resp[r >> 1], r & 1) + fbuf[r][tid] + b2v;
    ln24_norm(z, redbuf, n2gv, n2bv, tid);
    #pragma unroll
    for (int r = 0; r < NROW; ++r)
      *(__hip_bfloat16*)(hsb + swz(r, tid*2)) = f2bf(z[r]);
  }

  // ---------------- output: h[:,0] ----------------
  #pragma unroll
  for (int tt = 0; tt < TB; ++tt)
    out[(bt*TB + tt)*256 + tid] = z[tt*6];
}

// ---------------------------------------------------------------------------
// Fallback (pure-VALU, round-2 proven) if ws too small for weight staging.
__global__ __launch_bounds__(256, 2) void gb_fused_fallback(
    const float* __restrict__ x,
    const float* __restrict__ W_raw, const float* __restrict__ b_raw,
    const float* __restrict__ wl_emb, const float* __restrict__ pos_emb,
    const float* __restrict__ hop_emb,
    const float* __restrict__ ln_g, const float* __restrict__ ln_b,
    const float* __restrict__ Wqkv, const float* __restrict__ bqkv,
    const float* __restrict__ Wo,   const float* __restrict__ bo,
    const float* __restrict__ n1g,  const float* __restrict__ n1b,
    const float* __restrict__ W1,   const float* __restrict__ b1,
    const float* __restrict__ W2,   const float* __restrict__ b2,
    const float* __restrict__ n2g,  const float* __restrict__ n2b,
    const float* __restrict__ W_res, const float* __restrict__ b_res,
    float* __restrict__ out)
{
  __shared__ float hs[NROW][256];
  __shared__ __align__(16) char bufraw[NROW*768*2];
  __shared__ float attw[8][NROW][8];
  __shared__ float redbuf[192];

  __hip_bfloat16 (*qkvs)[768] = (__hip_bfloat16 (*)[768])bufraw;
  float (*fbuf)[256] = (float (*)[256])bufraw;
  float (*xbuf)[128] = (float (*)[128])bufraw;

  const int tid = threadIdx.x;
  const int bt  = blockIdx.x;

  for (int idx = tid; idx < TB*6*128; idx += 256) {
    int tt = idx / 768, rem = idx % 768;
    int s = rem >> 7, f = rem & 127;
    int t = bt*TB + tt, g = t >> 7, i = t & 127;
    int node;
    if (s < 2) node = i;
    else { int j = s - 2; node = (j < i) ? j : (j + 1); }
    xbuf[tt*6+s][f] = x[(g*128 + node)*128 + f];
  }
  __syncthreads();

  float z[NROW];
  {
    #pragma unroll
    for (int r = 0; r < NROW; ++r) z[r] = 0.f;
    #pragma unroll 4
    for (int f = 0; f < 128; ++f) {
      float w = W_raw[f*256 + tid];
      #pragma unroll
      for (int r = 0; r < NROW; ++r) z[r] += xbuf[r][f] * w;
    }
    float br  = b_raw[tid];
    float wl  = wl_emb[tid];
    float hp0 = hop_emb[5*256 + tid];
    float hp1 = hop_emb[511*256 + tid];
    float p[6];
    #pragma unroll
    for (int s = 0; s < 6; ++s) p[s] = pos_emb[s*256 + tid];
    #pragma unroll
    for (int r = 0; r < NROW; ++r) {
      int s = r % 6;
      z[r] += br + p[s] + wl + ((s < 2) ? hp0 : hp1);
    }
  }
  ln24_norm(z, redbuf, ln_g[tid], ln_b[tid], tid);
  #pragma unroll
  for (int r = 0; r < NROW; ++r) hs[r][tid] = z[r];

  float resv[NROW];
  #pragma unroll
  for (int r = 0; r < NROW; ++r) resv[r] = 0.f;
  if (bt < 64) {
    __syncthreads();
    for (int idx = tid; idx < TB*6*128; idx += 256) {
      int tt = idx / 768, rem = idx % 768;
      int s = rem >> 7, f = rem & 127;
      int t = bt*TB + tt;
      xbuf[tt*6+s][f] = x[(t*128 + s)*128 + f];
    }
    __syncthreads();
    #pragma unroll 4
    for (int f = 0; f < 128; ++f) {
      float w = W_res[f*256 + tid];
      #pragma unroll
      for (int r = 0; r < NROW; ++r) resv[r] += xbuf[r][f] * w;
    }
    float brr = b_res[tid];
    #pragma unroll
    for (int r = 0; r < NROW; ++r) resv[r] += brr;
  }

  for (int l = 0; l < 4; ++l) {
    const float* Wqkv_l = Wqkv + l*196608;
    const float* bqkv_l = bqkv + l*768;
    const float* Wo_l   = Wo   + l*65536;
    const float* bo_l   = bo   + l*256;
    const float* W1_l   = W1   + l*262144;
    const float* b1_l   = b1   + l*1024;
    const float* W2_l   = W2   + l*262144;
    const float* b2_l   = b2   + l*256;

    __syncthreads();

    for (int cg = 0; cg < 3; ++cg) {
      int col = cg*256 + tid;
      float acc[NROW];
      #pragma unroll
      for (int r = 0; r < NROW; ++r) acc[r] = 0.f;
      #pragma unroll 4
      for (int kk = 0; kk < 256; ++kk) {
        float w = Wqkv_l[kk*768 + col];
        #pragma unroll
        for (int r = 0; r < NROW; ++r) acc[r] += hs[r][kk] * w;
      }
      float bbv = bqkv_l[col];
      #pragma unroll
      for (int r = 0; r < NROW; ++r) qkvs[r][col] = f2bf(acc[r] + bbv);
    }
    __syncthreads();

    #pragma unroll 1
    for (int it = 0; it < 5; ++it) {
      int idx = it*256 + tid;
      if (idx < 1152) {
        int hh = idx / 144, rem = idx % 144;
        int r = rem / 6, sp = rem % 6;
        int tt6 = (r / 6) * 6;
        float sc = 0.f;
        #pragma unroll
        for (int c = 0; c < 32; ++c)
          sc += bf2f(qkvs[r][hh*32 + c]) * bf2f(qkvs[tt6 + sp][256 + hh*32 + c]);
        attw[hh][r][sp] = sc * 0.17677669529663687f;
      }
    }
    __syncthreads();

    if (tid < 192) {
      int hh = tid / 24, r = tid % 24;
      float mx = attw[hh][r][0];
      #pragma unroll
      for (int sp = 1; sp < 6; ++sp) mx = fmaxf(mx, attw[hh][r][sp]);
      float e[6], sum = 0.f;
      #pragma unroll
      for (int sp = 0; sp < 6; ++sp) { e[sp] = expf(attw[hh][r][sp] - mx); sum += e[sp]; }
      float inv = 1.f / sum;
      #pragma unroll
      for (int sp = 0; sp < 6; ++sp) attw[hh][r][sp] = e[sp] * inv;
    }
    __syncthreads();

    float oreg[NROW];
    {
      int hh = tid >> 5, c = tid & 31;
      #pragma unroll
      for (int r = 0; r < NROW; ++r) {
        int tt6 = (r / 6) * 6;
        float o = 0.f;
        #pragma unroll
        for (int sp = 0; sp < 6; ++sp)
          o += attw[hh][r][sp] * bf2f(qkvs[tt6 + sp][512 + hh*32 + c]);
        oreg[r] = o;
      }
    }
    __syncthreads();
    #pragma unroll
    for (int r = 0; r < NROW; ++r) fbuf[r][tid] = oreg[r];
    __syncthreads();

    {
      float bod = bo_l[tid];
      float zz[NROW];
      #pragma unroll
      for (int r = 0; r < NROW; ++r) zz[r] = bod;
      #pragma unroll 4
      for (int kk = 0; kk < 256; ++kk) {
        float w = Wo_l[kk*256 + tid];
        #pragma unroll
        for (int r = 0; r < NROW; ++r) zz[r] += fbuf[r][kk] * w;
      }
      #pragma unroll
      for (int r = 0; r < NROW; ++r) z[r] += zz[r] + resv[r];
    }
    ln24_norm(z, redbuf, n1g[l*256 + tid], n1b[l*256 + tid], tid);
    #pragma unroll
    for (int r = 0; r < NROW; ++r) hs[r][tid] = z[r];
    __syncthreads();

    float ff[NROW];
    {
      float b2d = b2_l[tid];
      #pragma unroll
      for (int r = 0; r < NROW; ++r) ff[r] = b2d;
    }
    for (int ch = 0; ch < 4; ++ch) {
      int j = ch*256 + tid;
      float gvv[NROW];
      float b1j = b1_l[j];
      #pragma unroll
      for (int r = 0; r < NROW; ++r) gvv[r] = b1j;
      #pragma unroll 4
      for (int kk = 0; kk < 256; ++kk) {
        float w = W1_l[kk*1024 + j];
        #pragma unroll
        for (int r = 0; r < NROW; ++r) gvv[r] += hs[r][kk] * w;
      }
      __syncthreads();
      #pragma unroll
      for (int r = 0; r < NROW; ++r) fbuf[r][tid] = gelu_f(gvv[r]);
      __syncthreads();
      #pragma unroll 4
      for (int kk = 0; kk < 256; ++kk) {
        float w = W2_l[(ch*256 + kk)*256 + tid];
        #pragma unroll
        for (int r = 0; r < NROW; ++r) ff[r] += fbuf[r][kk] * w;
      }
    }
    #pragma unroll
    for (int r = 0; r < NROW; ++r) z[r] += ff[r] + resv[r];
    ln24_norm(z, redbuf, n2g[l*256 + tid], n2b[l*256 + tid], tid);
    #pragma unroll
    for (int r = 0; r < NROW; ++r) hs[r][tid] = z[r];
  }

  __syncthreads();
  #pragma unroll
  for (int tt = 0; tt < TB; ++tt)
    out[(bt*TB + tt)*256 + tid] = hs[tt*6][tid];
}

extern "C" void kernel_launch(void* const* d_in, const int* in_sizes, int n_in,
                              void* d_out, int out_size, void* d_ws, size_t ws_size,
                              hipStream_t stream) {
  (void)in_sizes; (void)n_in; (void)out_size;
  const float* x      = (const float*)d_in[0];
  const float* W_raw  = (const float*)d_in[1];
  const float* b_raw  = (const float*)d_in[2];
  const float* wl_emb = (const float*)d_in[3];
  const float* pos_emb= (const float*)d_in[4];
  const float* hop_emb= (const float*)d_in[5];
  const float* ln_g   = (const float*)d_in[6];
  const float* ln_b   = (const float*)d_in[7];
  const float* Wqkv   = (const float*)d_in[8];
  const float* bqkv   = (const float*)d_in[9];
  const float* Wo     = (const float*)d_in[10];
  const float* bo     = (const float*)d_in[11];
  const float* n1g    = (const float*)d_in[12];
  const float* n1b    = (const float*)d_in[13];
  const float* W1     = (const float*)d_in[14];
  const float* b1     = (const float*)d_in[15];
  const float* W2     = (const float*)d_in[16];
  const float* b2     = (const float*)d_in[17];
  const float* n2g    = (const float*)d_in[18];
  const float* n2b    = (const float*)d_in[19];
  const float* W_res  = (const float*)d_in[20];
  const float* b_res  = (const float*)d_in[21];

  if (ws_size >= (size_t)WS_ELEMS * 2) {
    __hip_bfloat16* wsb = (__hip_bfloat16*)d_ws;
    gb_prep_kernel<<<1536, 256, 0, stream>>>(Wqkv, Wo, W1, W2, wsb);
    gb_mfma_kernel<<<8192, 256, 0, stream>>>(
        x, W_raw, b_raw, wl_emb, pos_emb, hop_emb, ln_g, ln_b,
        bqkv, bo, n1g, n1b, b1, b2, n2g, n2b, W_res, b_res,
        wsb, (float*)d_out);
  } else {
    gb_fused_fallback<<<8192, 256, 0, stream>>>(
        x, W_raw, b_raw, wl_emb, pos_emb, hop_emb, ln_g, ln_b,
        Wqkv, bqkv, Wo, bo, n1g, n1b, W1, b1, W2, b2, n2g, n2b,
        W_res, b_res, (float*)d_out);
  }
}